// Round 1
// baseline (466.677 us; speedup 1.0000x reference)
//
#include <hip/hip_runtime.h>

// Problem constants (fixed by setup_inputs): B=8, H=W=512, D=32, K=64
#define B_   8
#define N_   (512 * 512)   // H*W elements per batch
#define D_   32
#define K_   64
#define TPB  256
#define KROW 33            // padded LDS row (break stride-32 bank aliasing)
#define REC  (K_ * D_ + K_)  // per-block partial record: 2048 sums + 64 counts

// ---------------------------------------------------------------------------
// Stage 1: per-block partial segment sums.
// 8 lanes per element, each lane loads one float4 (16B) -> 4KB contiguous per
// 256-thread iteration. Accumulate in LDS (padded), write partial record.
// ---------------------------------------------------------------------------
__global__ __launch_bounds__(TPB) void seg_partial_kernel(
    const float* __restrict__ emb, const int* __restrict__ lab,
    float* __restrict__ partials, int blk_per_b)
{
    __shared__ float s_sum[K_ * KROW];
    __shared__ float s_cnt[K_];

    for (int i = threadIdx.x; i < K_ * KROW; i += TPB) s_sum[i] = 0.f;
    if (threadIdx.x < K_) s_cnt[threadIdx.x] = 0.f;
    __syncthreads();

    const int blk = blockIdx.x;
    const int b   = blk / blk_per_b;
    const int bib = blk - b * blk_per_b;
    const int d4  = threadIdx.x & 7;   // which float4 of the 8 in this element
    const int eg  = threadIdx.x >> 3;  // element slot 0..31 within iteration
    const long long batch_base = (long long)b * N_;
    const float4* __restrict__ embv = reinterpret_cast<const float4*>(emb);

    for (int base = bib * 32; base < N_; base += blk_per_b * 32) {
        long long e = batch_base + base + eg;
        int lb = lab[e];
        float4 v = embv[e * 8 + d4];
        int a = lb * KROW + d4 * 4;
        atomicAdd(&s_sum[a + 0], v.x);
        atomicAdd(&s_sum[a + 1], v.y);
        atomicAdd(&s_sum[a + 2], v.z);
        atomicAdd(&s_sum[a + 3], v.w);
        if (d4 == 0) atomicAdd(&s_cnt[lb], 1.0f);
    }
    __syncthreads();

    float* out = partials + (size_t)blk * REC;
    for (int i = threadIdx.x; i < K_ * D_; i += TPB)
        out[i] = s_sum[(i >> 5) * KROW + (i & 31)];
    if (threadIdx.x < K_)
        out[K_ * D_ + threadIdx.x] = s_cnt[threadIdx.x];
}

// ---------------------------------------------------------------------------
// Stage 2: reduce the per-block partials into final sums (B,K,D) + counts (B,K).
// One thread per output scalar. Layout of sums_cnts: [B*K*D sums][B*K counts].
// ---------------------------------------------------------------------------
__global__ __launch_bounds__(TPB) void seg_reduce_kernel(
    const float* __restrict__ partials, float* __restrict__ sums_cnts,
    int blk_per_b)
{
    int idx = blockIdx.x * TPB + threadIdx.x;
    if (idx < B_ * K_ * D_) {
        int b = idx / (K_ * D_);
        int r = idx - b * (K_ * D_);
        const float* p = partials + (size_t)b * blk_per_b * REC + r;
        float acc = 0.f;
        for (int i = 0; i < blk_per_b; ++i) acc += p[(size_t)i * REC];
        sums_cnts[idx] = acc;
    } else if (idx < B_ * K_ * D_ + B_ * K_) {
        int c = idx - B_ * K_ * D_;
        int b = c / K_;
        int k = c - b * K_;
        const float* p = partials + (size_t)b * blk_per_b * REC + K_ * D_ + k;
        float acc = 0.f;
        for (int i = 0; i < blk_per_b; ++i) acc += p[(size_t)i * REC];
        sums_cnts[idx] = acc;
    }
}

// ---------------------------------------------------------------------------
// Stage 3: single block computes the push loss and writes mean to out[0].
// Centroids staged in LDS with +1 padding (pair loop reads stride-KROW ->
// bank index (k + d) % 32, conflict-free-ish instead of 32-way at stride 32).
// ---------------------------------------------------------------------------
__global__ __launch_bounds__(TPB) void loss_kernel(
    const float* __restrict__ sums_cnts, float* __restrict__ out)
{
    __shared__ float s_cent[K_ * KROW];
    __shared__ float s_pres[K_];
    __shared__ float s_red[TPB];

    const float* sums = sums_cnts;
    const float* cnts = sums_cnts + B_ * K_ * D_;

    float total = 0.f;  // only thread 0's copy is used
    for (int b = 0; b < B_; ++b) {
        for (int i = threadIdx.x; i < K_ * D_; i += TPB) {
            int k = i >> 5, d = i & 31;
            float c = cnts[b * K_ + k];
            s_cent[k * KROW + d] = sums[(size_t)b * K_ * D_ + i] / fmaxf(c, 1.0f);
        }
        if (threadIdx.x < K_)
            s_pres[threadIdx.x] = (cnts[b * K_ + threadIdx.x] > 0.5f) ? 1.f : 0.f;
        __syncthreads();

        float acc = 0.f;
        for (int p = threadIdx.x; p < K_ * K_; p += TPB) {
            int k1 = p >> 6, k2 = p & 63;
            if (k1 < k2 && s_pres[k1] > 0.5f && s_pres[k2] > 0.5f) {
                float dist = 0.f;
#pragma unroll
                for (int d = 0; d < D_; ++d)
                    dist += fabsf(s_cent[k1 * KROW + d] - s_cent[k2 * KROW + d]);
                float h = fmaxf(0.25f - dist, 0.f);
                acc += h * h;
            }
        }
        s_red[threadIdx.x] = acc;
        __syncthreads();
        for (int s = TPB / 2; s > 0; s >>= 1) {
            if (threadIdx.x < s) s_red[threadIdx.x] += s_red[threadIdx.x + s];
            __syncthreads();
        }
        if (threadIdx.x == 0) {
            float n = 0.f;
            for (int k = 0; k < K_; ++k) n += s_pres[k];
            float ncomp = n * (n - 1.f) * 0.5f;
            total += (ncomp > 0.f) ? (s_red[0] / ncomp) : 0.f;
        }
        __syncthreads();
    }
    if (threadIdx.x == 0) out[0] = total / (float)B_;
}

// ---------------------------------------------------------------------------
extern "C" void kernel_launch(void* const* d_in, const int* in_sizes, int n_in,
                              void* d_out, int out_size, void* d_ws, size_t ws_size,
                              hipStream_t stream)
{
    const float* emb = (const float*)d_in[0];
    const int*   lab = (const int*)d_in[1];
    float*       out = (float*)d_out;
    float*       ws  = (float*)d_ws;

    // Choose partial-block count to fit workspace (primary: 128 blocks/batch).
    int blk_per_b = 128;
    const size_t final_floats = (size_t)(B_ * K_ * D_ + B_ * K_);
    while (blk_per_b > 1) {
        size_t need = ((size_t)(blk_per_b * B_) * REC + final_floats) * sizeof(float);
        if (need <= ws_size) break;
        blk_per_b >>= 1;
    }
    const int nblk = blk_per_b * B_;

    float* partials  = ws;
    float* sums_cnts = ws + (size_t)nblk * REC;

    seg_partial_kernel<<<nblk, TPB, 0, stream>>>(emb, lab, partials, blk_per_b);

    const int tot = B_ * K_ * D_ + B_ * K_;
    seg_reduce_kernel<<<(tot + TPB - 1) / TPB, TPB, 0, stream>>>(
        partials, sums_cnts, blk_per_b);

    loss_kernel<<<1, TPB, 0, stream>>>(sums_cnts, out);
}

// Round 2
// 188.972 us; speedup vs baseline: 2.4696x; 2.4696x over previous
//
#include <hip/hip_runtime.h>

// Problem constants (fixed by setup_inputs): B=8, H=W=512, D=32, K=64
#define B_    8
#define N_    (512 * 512)
#define D_    32
#define K_    64
#define TPB   256
#define NWAVE (TPB / 64)
#define KROW  36                 // row stride (floats): 16B-aligned, spreads banks
#define TABW  (K_ * KROW)        // 2304 floats per wave-private table
#define REC   (K_ * D_ + K_)     // per-block partial record: 2048 sums + 64 counts

// ---------------------------------------------------------------------------
// Stage 1: per-block partial segment sums, NO ATOMICS.
// Per wave-iteration: 8 elements x 8 d4-lanes. Labels come in via wave-uniform
// scalar loads; each lane computes its element's duplicate "order"; round r
// lets elements with order==r do a plain LDS float4 RMW (race-free: distinct
// labels within a round, distinct d4 within an element, per-wave tables).
// ---------------------------------------------------------------------------
__global__ __launch_bounds__(TPB) void seg_partial_kernel(
    const float* __restrict__ emb, const int* __restrict__ lab,
    float* __restrict__ partials, int blk_per_b)
{
    __shared__ __align__(16) float s_tab[NWAVE * TABW];
    __shared__ float s_cnt[NWAVE * K_];

    for (int i = threadIdx.x; i < NWAVE * TABW; i += TPB) s_tab[i] = 0.f;
    for (int i = threadIdx.x; i < NWAVE * K_; i += TPB) s_cnt[i] = 0.f;
    __syncthreads();

    const int tid  = threadIdx.x;
    const int wave = tid >> 6;
    const int lane = tid & 63;
    const int egl  = lane >> 3;          // element slot within wave: 0..7
    const int d4   = lane & 7;           // float4 slice within element: 0..7
    const int eg   = wave * 8 + egl;     // element slot within block-iter: 0..31

    float* tab = s_tab + wave * TABW;
    float* cnt = s_cnt + wave * K_;

    const int blk = blockIdx.x;
    const int b   = blk / blk_per_b;
    const int bib = blk - b * blk_per_b;
    const long long bbase = (long long)b * N_;
    const float4* __restrict__ embv = reinterpret_cast<const float4*>(emb);
    const int STEP = blk_per_b * 32;

    const int wb = __builtin_amdgcn_readfirstlane(wave * 8);

    int base = bib * 32;
    // prologue loads (iteration 0)
    const int* lp = lab + bbase + base + wb;
    int l0 = lp[0], l1 = lp[1], l2 = lp[2], l3 = lp[3],
        l4 = lp[4], l5 = lp[5], l6 = lp[6], l7 = lp[7];
    float4 v = embv[(bbase + base + eg) * 8 + d4];

    while (base < N_) {
        const int nbase = base + STEP;

        // my element's label (cndmask tree over the 8 scalar labels)
        int lb = egl < 4 ? (egl < 2 ? (egl == 0 ? l0 : l1) : (egl == 2 ? l2 : l3))
                         : (egl < 6 ? (egl == 4 ? l4 : l5) : (egl == 6 ? l6 : l7));

        // order = #earlier elements in this wave with the same label
        unsigned order = 0;
        order += (0 < egl) && (lb == l0);
        order += (1 < egl) && (lb == l1);
        order += (2 < egl) && (lb == l2);
        order += (3 < egl) && (lb == l3);
        order += (4 < egl) && (lb == l4);
        order += (5 < egl) && (lb == l5);
        order += (6 < egl) && (lb == l6);

        // prefetch next iteration (issued before the rounds so the latency
        // hides under the LDS RMW work)
        int t0 = 0, t1 = 0, t2 = 0, t3 = 0, t4 = 0, t5 = 0, t6 = 0, t7 = 0;
        float4 vn = make_float4(0.f, 0.f, 0.f, 0.f);
        if (nbase < N_) {
            const int* lpn = lab + bbase + nbase + wb;
            t0 = lpn[0]; t1 = lpn[1]; t2 = lpn[2]; t3 = lpn[3];
            t4 = lpn[4]; t5 = lpn[5]; t6 = lpn[6]; t7 = lpn[7];
            vn = embv[(bbase + nbase + eg) * 8 + d4];
        }

        // duplicate-resolution rounds (expected ~1.4 rounds)
        const int a = lb * KROW + d4 * 4;
        for (int r = 0; r < 8; ++r) {
            if ((int)order == r) {
                float4 cur = *reinterpret_cast<const float4*>(tab + a);
                cur.x += v.x; cur.y += v.y; cur.z += v.z; cur.w += v.w;
                *reinterpret_cast<float4*>(tab + a) = cur;
                if (d4 == 0) cnt[lb] += 1.0f;
            }
            __builtin_amdgcn_sched_barrier(0);  // pin round ordering
            if (!__any((int)(order > (unsigned)r))) break;
        }

        base = nbase;
        l0 = t0; l1 = t1; l2 = t2; l3 = t3;
        l4 = t4; l5 = t5; l6 = t6; l7 = t7;
        v = vn;
    }
    __syncthreads();

    // merge the 4 wave tables, write one partial record per block
    float* out = partials + (size_t)blk * REC;
    for (int i = tid; i < K_ * D_; i += TPB) {
        int k = i >> 5, d = i & 31;
        float s = 0.f;
#pragma unroll
        for (int w = 0; w < NWAVE; ++w) s += s_tab[w * TABW + k * KROW + d];
        out[i] = s;
    }
    if (tid < K_) {
        float c = 0.f;
#pragma unroll
        for (int w = 0; w < NWAVE; ++w) c += s_cnt[w * K_ + tid];
        out[K_ * D_ + tid] = c;
    }
}

// ---------------------------------------------------------------------------
// Stage 2: reduce per-block partials into final sums (B,K,D) + counts (B,K).
// ---------------------------------------------------------------------------
__global__ __launch_bounds__(TPB) void seg_reduce_kernel(
    const float* __restrict__ partials, float* __restrict__ sums_cnts,
    int blk_per_b)
{
    int idx = blockIdx.x * TPB + threadIdx.x;
    if (idx < B_ * K_ * D_) {
        int b = idx / (K_ * D_);
        int r = idx - b * (K_ * D_);
        const float* p = partials + (size_t)b * blk_per_b * REC + r;
        float acc = 0.f;
        for (int i = 0; i < blk_per_b; ++i) acc += p[(size_t)i * REC];
        sums_cnts[idx] = acc;
    } else if (idx < B_ * K_ * D_ + B_ * K_) {
        int c = idx - B_ * K_ * D_;
        int b = c / K_;
        int k = c - b * K_;
        const float* p = partials + (size_t)b * blk_per_b * REC + K_ * D_ + k;
        float acc = 0.f;
        for (int i = 0; i < blk_per_b; ++i) acc += p[(size_t)i * REC];
        sums_cnts[idx] = acc;
    }
}

// ---------------------------------------------------------------------------
// Stage 3: single block computes the push loss and writes mean to out[0].
// ---------------------------------------------------------------------------
__global__ __launch_bounds__(TPB) void loss_kernel(
    const float* __restrict__ sums_cnts, float* __restrict__ out)
{
    __shared__ float s_cent[K_ * 33];
    __shared__ float s_pres[K_];
    __shared__ float s_red[TPB];

    const float* sums = sums_cnts;
    const float* cnts = sums_cnts + B_ * K_ * D_;

    float total = 0.f;  // only thread 0's copy is used
    for (int b = 0; b < B_; ++b) {
        for (int i = threadIdx.x; i < K_ * D_; i += TPB) {
            int k = i >> 5, d = i & 31;
            float c = cnts[b * K_ + k];
            s_cent[k * 33 + d] = sums[(size_t)b * K_ * D_ + i] / fmaxf(c, 1.0f);
        }
        if (threadIdx.x < K_)
            s_pres[threadIdx.x] = (cnts[b * K_ + threadIdx.x] > 0.5f) ? 1.f : 0.f;
        __syncthreads();

        float acc = 0.f;
        for (int p = threadIdx.x; p < K_ * K_; p += TPB) {
            int k1 = p >> 6, k2 = p & 63;
            if (k1 < k2 && s_pres[k1] > 0.5f && s_pres[k2] > 0.5f) {
                float dist = 0.f;
#pragma unroll
                for (int d = 0; d < D_; ++d)
                    dist += fabsf(s_cent[k1 * 33 + d] - s_cent[k2 * 33 + d]);
                float h = fmaxf(0.25f - dist, 0.f);
                acc += h * h;
            }
        }
        s_red[threadIdx.x] = acc;
        __syncthreads();
        for (int s = TPB / 2; s > 0; s >>= 1) {
            if (threadIdx.x < s) s_red[threadIdx.x] += s_red[threadIdx.x + s];
            __syncthreads();
        }
        if (threadIdx.x == 0) {
            float n = 0.f;
            for (int k = 0; k < K_; ++k) n += s_pres[k];
            float ncomp = n * (n - 1.f) * 0.5f;
            total += (ncomp > 0.f) ? (s_red[0] / ncomp) : 0.f;
        }
        __syncthreads();
    }
    if (threadIdx.x == 0) out[0] = total / (float)B_;
}

// ---------------------------------------------------------------------------
extern "C" void kernel_launch(void* const* d_in, const int* in_sizes, int n_in,
                              void* d_out, int out_size, void* d_ws, size_t ws_size,
                              hipStream_t stream)
{
    const float* emb = (const float*)d_in[0];
    const int*   lab = (const int*)d_in[1];
    float*       out = (float*)d_out;
    float*       ws  = (float*)d_ws;

    int blk_per_b = 128;
    const size_t final_floats = (size_t)(B_ * K_ * D_ + B_ * K_);
    while (blk_per_b > 1) {
        size_t need = ((size_t)(blk_per_b * B_) * REC + final_floats) * sizeof(float);
        if (need <= ws_size) break;
        blk_per_b >>= 1;
    }
    const int nblk = blk_per_b * B_;

    float* partials  = ws;
    float* sums_cnts = ws + (size_t)nblk * REC;

    seg_partial_kernel<<<nblk, TPB, 0, stream>>>(emb, lab, partials, blk_per_b);

    const int tot = B_ * K_ * D_ + B_ * K_;
    seg_reduce_kernel<<<(tot + TPB - 1) / TPB, TPB, 0, stream>>>(
        partials, sums_cnts, blk_per_b);

    loss_kernel<<<1, TPB, 0, stream>>>(sums_cnts, out);
}

// Round 3
// 109.701 us; speedup vs baseline: 4.2541x; 1.7226x over previous
//
#include <hip/hip_runtime.h>

// Problem constants (fixed by setup_inputs): B=8, H=W=512, D=32, K=64
#define B_    8
#define N_    (512 * 512)
#define D_    32
#define K_    64
#define TPB   256
#define NWAVE (TPB / 64)
#define KROW  36                 // row stride (floats): 16B-aligned, spreads banks
#define TABW  (K_ * KROW)        // 2304 floats per wave-private table
#define REC   (K_ * D_ + K_)     // per-block partial record: 2048 sums + 64 counts

// ---------------------------------------------------------------------------
// Stage 1: per-block partial segment sums, NO ATOMICS (unchanged from r2).
// ---------------------------------------------------------------------------
__global__ __launch_bounds__(TPB) void seg_partial_kernel(
    const float* __restrict__ emb, const int* __restrict__ lab,
    float* __restrict__ partials, int blk_per_b)
{
    __shared__ __align__(16) float s_tab[NWAVE * TABW];
    __shared__ float s_cnt[NWAVE * K_];

    for (int i = threadIdx.x; i < NWAVE * TABW; i += TPB) s_tab[i] = 0.f;
    for (int i = threadIdx.x; i < NWAVE * K_; i += TPB) s_cnt[i] = 0.f;
    __syncthreads();

    const int tid  = threadIdx.x;
    const int wave = tid >> 6;
    const int lane = tid & 63;
    const int egl  = lane >> 3;          // element slot within wave: 0..7
    const int d4   = lane & 7;           // float4 slice within element: 0..7
    const int eg   = wave * 8 + egl;     // element slot within block-iter: 0..31

    float* tab = s_tab + wave * TABW;
    float* cnt = s_cnt + wave * K_;

    const int blk = blockIdx.x;
    const int b   = blk / blk_per_b;
    const int bib = blk - b * blk_per_b;
    const long long bbase = (long long)b * N_;
    const float4* __restrict__ embv = reinterpret_cast<const float4*>(emb);
    const int STEP = blk_per_b * 32;

    const int wb = __builtin_amdgcn_readfirstlane(wave * 8);

    int base = bib * 32;
    // prologue loads (iteration 0)
    const int* lp = lab + bbase + base + wb;
    int l0 = lp[0], l1 = lp[1], l2 = lp[2], l3 = lp[3],
        l4 = lp[4], l5 = lp[5], l6 = lp[6], l7 = lp[7];
    float4 v = embv[(bbase + base + eg) * 8 + d4];

    while (base < N_) {
        const int nbase = base + STEP;

        // my element's label (cndmask tree over the 8 scalar labels)
        int lb = egl < 4 ? (egl < 2 ? (egl == 0 ? l0 : l1) : (egl == 2 ? l2 : l3))
                         : (egl < 6 ? (egl == 4 ? l4 : l5) : (egl == 6 ? l6 : l7));

        // order = #earlier elements in this wave with the same label
        unsigned order = 0;
        order += (0 < egl) && (lb == l0);
        order += (1 < egl) && (lb == l1);
        order += (2 < egl) && (lb == l2);
        order += (3 < egl) && (lb == l3);
        order += (4 < egl) && (lb == l4);
        order += (5 < egl) && (lb == l5);
        order += (6 < egl) && (lb == l6);

        // prefetch next iteration
        int t0 = 0, t1 = 0, t2 = 0, t3 = 0, t4 = 0, t5 = 0, t6 = 0, t7 = 0;
        float4 vn = make_float4(0.f, 0.f, 0.f, 0.f);
        if (nbase < N_) {
            const int* lpn = lab + bbase + nbase + wb;
            t0 = lpn[0]; t1 = lpn[1]; t2 = lpn[2]; t3 = lpn[3];
            t4 = lpn[4]; t5 = lpn[5]; t6 = lpn[6]; t7 = lpn[7];
            vn = embv[(bbase + nbase + eg) * 8 + d4];
        }

        // duplicate-resolution rounds (expected ~1.4 rounds)
        const int a = lb * KROW + d4 * 4;
        for (int r = 0; r < 8; ++r) {
            if ((int)order == r) {
                float4 cur = *reinterpret_cast<const float4*>(tab + a);
                cur.x += v.x; cur.y += v.y; cur.z += v.z; cur.w += v.w;
                *reinterpret_cast<float4*>(tab + a) = cur;
                if (d4 == 0) cnt[lb] += 1.0f;
            }
            __builtin_amdgcn_sched_barrier(0);  // pin round ordering
            if (!__any((int)(order > (unsigned)r))) break;
        }

        base = nbase;
        l0 = t0; l1 = t1; l2 = t2; l3 = t3;
        l4 = t4; l5 = t5; l6 = t6; l7 = t7;
        v = vn;
    }
    __syncthreads();

    // merge the 4 wave tables, write one partial record per block
    float* out = partials + (size_t)blk * REC;
    for (int i = tid; i < K_ * D_; i += TPB) {
        int k = i >> 5, d = i & 31;
        float s = 0.f;
#pragma unroll
        for (int w = 0; w < NWAVE; ++w) s += s_tab[w * TABW + k * KROW + d];
        out[i] = s;
    }
    if (tid < K_) {
        float c = 0.f;
#pragma unroll
        for (int w = 0; w < NWAVE; ++w) c += s_cnt[w * K_ + tid];
        out[K_ * D_ + tid] = c;
    }
}

// ---------------------------------------------------------------------------
// Stage 2: reduce per-block partials into final sums (B,K,D) + counts (B,K).
// ---------------------------------------------------------------------------
__global__ __launch_bounds__(TPB) void seg_reduce_kernel(
    const float* __restrict__ partials, float* __restrict__ sums_cnts,
    int blk_per_b)
{
    int idx = blockIdx.x * TPB + threadIdx.x;
    if (idx < B_ * K_ * D_) {
        int b = idx / (K_ * D_);
        int r = idx - b * (K_ * D_);
        const float* p = partials + (size_t)b * blk_per_b * REC + r;
        float acc = 0.f;
        for (int i = 0; i < blk_per_b; ++i) acc += p[(size_t)i * REC];
        sums_cnts[idx] = acc;
    } else if (idx < B_ * K_ * D_ + B_ * K_) {
        int c = idx - B_ * K_ * D_;
        int b = c / K_;
        int k = c - b * K_;
        const float* p = partials + (size_t)b * blk_per_b * REC + K_ * D_ + k;
        float acc = 0.f;
        for (int i = 0; i < blk_per_b; ++i) acc += p[(size_t)i * REC];
        sums_cnts[idx] = acc;
    }
}

// ---------------------------------------------------------------------------
// Stage 3: one block per batch. Centroids staged TRANSPOSED in LDS as
// float4 s_cent4[j=0..7][k=0..63]: lane-sweeps-k is the canonical
// full-throughput ds_read_b128 pattern; k1 reads are wave-uniform broadcasts.
// Each lane caches its own k2=lane centroid in 8 float4 regs; wave w sweeps
// k1 = w*16..w*16+15. Per-batch loss -> batch_loss[b].
// ---------------------------------------------------------------------------
__global__ __launch_bounds__(TPB) void loss8_kernel(
    const float* __restrict__ sums_cnts, float* __restrict__ batch_loss)
{
    __shared__ __align__(16) float4 s_cent4[8 * K_];  // [j][k]
    __shared__ float s_pres[K_];
    __shared__ float s_wred[NWAVE];

    const int b   = blockIdx.x;
    const int tid = threadIdx.x;
    const float* sums = sums_cnts + (size_t)b * K_ * D_;
    const float* cnts = sums_cnts + (size_t)B_ * K_ * D_ + b * K_;

    for (int i = tid; i < 8 * K_; i += TPB) {
        int j = i >> 6, k = i & 63;
        float inv = 1.0f / fmaxf(cnts[k], 1.0f);
        const float* s = sums + k * D_ + j * 4;
        s_cent4[i] = make_float4(s[0] * inv, s[1] * inv, s[2] * inv, s[3] * inv);
    }
    if (tid < K_) s_pres[tid] = (cnts[tid] > 0.5f) ? 1.f : 0.f;
    __syncthreads();

    const int wave = tid >> 6, lane = tid & 63;

    // own centroid row (k2 = lane), 8 float4 regs
    float4 cb[8];
#pragma unroll
    for (int j = 0; j < 8; ++j) cb[j] = s_cent4[j * K_ + lane];
    const float pres2 = s_pres[lane];

    float acc = 0.f;
#pragma unroll 4
    for (int t = 0; t < 16; ++t) {
        const int k1 = wave * 16 + t;
        float dist = 0.f;
#pragma unroll
        for (int j = 0; j < 8; ++j) {
            float4 a = s_cent4[j * K_ + k1];   // wave-uniform broadcast
            dist += fabsf(a.x - cb[j].x) + fabsf(a.y - cb[j].y)
                  + fabsf(a.z - cb[j].z) + fabsf(a.w - cb[j].w);
        }
        float h = fmaxf(0.25f - dist, 0.f);
        float valid = (k1 < lane) ? s_pres[k1] * pres2 : 0.f;
        acc += valid * h * h;
    }
    // 64-lane butterfly reduce
#pragma unroll
    for (int m = 32; m > 0; m >>= 1) acc += __shfl_xor(acc, m);
    if (lane == 0) s_wred[wave] = acc;
    __syncthreads();
    if (tid == 0) {
        float s = s_wred[0] + s_wred[1] + s_wred[2] + s_wred[3];
        float n = 0.f;
        for (int k = 0; k < K_; ++k) n += s_pres[k];
        float ncomp = n * (n - 1.f) * 0.5f;
        batch_loss[b] = (ncomp > 0.f) ? (s / ncomp) : 0.f;
    }
}

// ---------------------------------------------------------------------------
// Stage 4: average the 8 per-batch losses into out[0].
// ---------------------------------------------------------------------------
__global__ void final_kernel(const float* __restrict__ batch_loss,
                             float* __restrict__ out)
{
    if (threadIdx.x == 0) {
        float t = 0.f;
#pragma unroll
        for (int b = 0; b < B_; ++b) t += batch_loss[b];
        out[0] = t * (1.0f / (float)B_);
    }
}

// ---------------------------------------------------------------------------
extern "C" void kernel_launch(void* const* d_in, const int* in_sizes, int n_in,
                              void* d_out, int out_size, void* d_ws, size_t ws_size,
                              hipStream_t stream)
{
    const float* emb = (const float*)d_in[0];
    const int*   lab = (const int*)d_in[1];
    float*       out = (float*)d_out;
    float*       ws  = (float*)d_ws;

    int blk_per_b = 128;
    const size_t tail_floats = (size_t)(B_ * K_ * D_ + B_ * K_) + B_;
    while (blk_per_b > 1) {
        size_t need = ((size_t)(blk_per_b * B_) * REC + tail_floats) * sizeof(float);
        if (need <= ws_size) break;
        blk_per_b >>= 1;
    }
    const int nblk = blk_per_b * B_;

    float* partials   = ws;
    float* sums_cnts  = ws + (size_t)nblk * REC;
    float* batch_loss = sums_cnts + (size_t)(B_ * K_ * D_ + B_ * K_);

    seg_partial_kernel<<<nblk, TPB, 0, stream>>>(emb, lab, partials, blk_per_b);

    const int tot = B_ * K_ * D_ + B_ * K_;
    seg_reduce_kernel<<<(tot + TPB - 1) / TPB, TPB, 0, stream>>>(
        partials, sums_cnts, blk_per_b);

    loss8_kernel<<<B_, TPB, 0, stream>>>(sums_cnts, batch_loss);

    final_kernel<<<1, 64, 0, stream>>>(batch_loss, out);
}